// Round 16
// baseline (2145.579 us; speedup 1.0000x reference)
//
#include <hip/hip_runtime.h>

#define BATCH   8
#define NPTS    16384
#define NCH     128
#define NPOINT  1024
#define NSAMPLE 64
#define CIN     131   // 3 + NCH

#define THREADS  1024
#define TPP      (NPTS / THREADS)   // 16 points per thread (8 float2 pairs)
#define CTAG     0x7C000000u

typedef unsigned long long u64;
typedef float f32x2 __attribute__((ext_vector_type(2)));

__device__ __forceinline__ u64 u64max(u64 a, u64 b) { return a > b ? a : b; }

// 64-lane f32 max via DPP (VALU latency). xor1,xor2 (quad_perm), row_half_
// mirror, row_mirror, row_bcast15, row_bcast31; result uniform via readlane 63.
__device__ __forceinline__ float dpp_wave_max_f32(float v) {
  float o;
  o = __int_as_float(__builtin_amdgcn_update_dpp(
        __float_as_int(v), __float_as_int(v), 0xB1, 0xF, 0xF, false));
  v = fmaxf(v, o);
  o = __int_as_float(__builtin_amdgcn_update_dpp(
        __float_as_int(v), __float_as_int(v), 0x4E, 0xF, 0xF, false));
  v = fmaxf(v, o);
  o = __int_as_float(__builtin_amdgcn_update_dpp(
        __float_as_int(v), __float_as_int(v), 0x141, 0xF, 0xF, false));
  v = fmaxf(v, o);
  o = __int_as_float(__builtin_amdgcn_update_dpp(
        __float_as_int(v), __float_as_int(v), 0x140, 0xF, 0xF, false));
  v = fmaxf(v, o);
  o = __int_as_float(__builtin_amdgcn_update_dpp(
        __float_as_int(v), __float_as_int(v), 0x142, 0xF, 0xF, false));
  v = fmaxf(v, o);
  o = __int_as_float(__builtin_amdgcn_update_dpp(
        __float_as_int(v), __float_as_int(v), 0x143, 0xF, 0xF, false));
  v = fmaxf(v, o);
  return __int_as_float(__builtin_amdgcn_readlane(__float_as_int(v), 63));
}

__device__ __forceinline__ unsigned dpp_wave_min_u32(unsigned v) {
  unsigned o;
  o = (unsigned)__builtin_amdgcn_update_dpp((int)v, (int)v, 0xB1, 0xF, 0xF, false);
  v = min(v, o);
  o = (unsigned)__builtin_amdgcn_update_dpp((int)v, (int)v, 0x4E, 0xF, 0xF, false);
  v = min(v, o);
  o = (unsigned)__builtin_amdgcn_update_dpp((int)v, (int)v, 0x141, 0xF, 0xF, false);
  v = min(v, o);
  o = (unsigned)__builtin_amdgcn_update_dpp((int)v, (int)v, 0x140, 0xF, 0xF, false);
  v = min(v, o);
  o = (unsigned)__builtin_amdgcn_update_dpp((int)v, (int)v, 0x142, 0xF, 0xF, false);
  v = min(v, o);
  o = (unsigned)__builtin_amdgcn_update_dpp((int)v, (int)v, 0x143, 0xF, 0xF, false);
  v = min(v, o);
  return (unsigned)__builtin_amdgcn_readlane((int)v, 63);
}

// ---------------------------------------------------------------------------
// Transpose weights into [ic][oc] layout (float4 loads in the MLP).
// ---------------------------------------------------------------------------
__global__ void wtrans_kernel(const float* __restrict__ W0,
                              const float* __restrict__ W1,
                              const float* __restrict__ W2,
                              float* __restrict__ w0t,
                              float* __restrict__ w1t,
                              float* __restrict__ w2t)
{
  const int t = blockIdx.x * blockDim.x + threadIdx.x;
  if (t < 64 * CIN) { const int oc = t / CIN, ic = t % CIN; w0t[ic * 64  + oc] = W0[t]; }
  if (t < 64 * 64)  { const int oc = t >> 6,  ic = t & 63;  w1t[ic * 64  + oc] = W1[t]; }
  if (t < 128 * 64) { const int oc = t / 64,  ic = t % 64;  w2t[ic * 128 + oc] = W2[t]; }
}

// ---------------------------------------------------------------------------
// Mega kernel (R12/R15 structure; inner loop now uses EXPLICIT inline-asm
// v_pk_add_f32 / v_pk_mul_f32 — guaranteed 2-wide packed f32, halving the
// pk-able instruction count. Numerics bit-exact: a-b == a+(-b) in IEEE, and
// each mul/add rounds separately == numpy ((dx*dx+dy*dy)+dz*dz), no fma.
// Pair layout keeps ascending global index for first-occurrence argmax.)
// bids 0..7: FPS, one 1024-thread block per batch; ONE barrier/iter (parity
// LDS slots); DPP wave argmax; uniform coord load. bids 8..8199: one block
// per center (pc-major): spin on tagged slot -> ballquery -> gather -> MLP.
// ---------------------------------------------------------------------------
__global__ __launch_bounds__(THREADS) void mega_kernel(
    const float* __restrict__ xyz, const float* __restrict__ feat,
    const float* __restrict__ w0t, const float* __restrict__ b0,
    const float* __restrict__ w1t, const float* __restrict__ b1,
    const float* __restrict__ w2t, const float* __restrict__ b2,
    float* __restrict__ out_newxyz, float* __restrict__ out_feat,
    float* __restrict__ out_inds_f, u64* __restrict__ cslot)
{
  __shared__ float sA[CIN * 64];     // grouped x (131x64); reused as h2
  __shared__ float sB[64 * 64];      // h1
  __shared__ int   s_idx[NSAMPLE];
  __shared__ int   bq[4][NSAMPLE];
  __shared__ int   bqcnt[4], bqfirst[4];
  __shared__ u64   s_w[2][16];
  __shared__ unsigned s_sel[4];

  const int t = threadIdx.x;

  if (blockIdx.x < BATCH) {
    // ======================= FPS path =======================
    const int b = blockIdx.x;
    const int lane = t & 63, wid = t >> 6;
    const float* __restrict__ p = xyz + (size_t)b * NPTS * 3;

    f32x2 xs2[TPP / 2], ys2[TPP / 2], zs2[TPP / 2], mind2[TPP / 2];
#pragma unroll
    for (int j = 0; j < TPP / 2; ++j) {
      const int n0 = t + (2 * j) * THREADS;      // coalesced per wave
      const int n1 = t + (2 * j + 1) * THREADS;
      xs2[j] = (f32x2){p[n0 * 3 + 0], p[n1 * 3 + 0]};
      ys2[j] = (f32x2){p[n0 * 3 + 1], p[n1 * 3 + 1]};
      zs2[j] = (f32x2){p[n0 * 3 + 2], p[n1 * 3 + 2]};
      mind2[j] = (f32x2){1e10f, 1e10f};
    }

    u64* __restrict__ cs = cslot + (size_t)b * NPOINT * 4;

    float px = p[0], py = p[1], pz = p[2];
    if (t == 0) {
      out_inds_f[b * NPOINT] = 0.0f;
      const size_t o = (size_t)b * NPOINT * 3;
      out_newxyz[o + 0] = px; out_newxyz[o + 1] = py; out_newxyz[o + 2] = pz;
      const u64 tg = (u64)CTAG << 32;
      __hip_atomic_store(&cs[1], tg | __float_as_uint(px), __ATOMIC_RELAXED, __HIP_MEMORY_SCOPE_AGENT);
      __hip_atomic_store(&cs[2], tg | __float_as_uint(py), __ATOMIC_RELAXED, __HIP_MEMORY_SCOPE_AGENT);
      __hip_atomic_store(&cs[3], tg | __float_as_uint(pz), __ATOMIC_RELAXED, __HIP_MEMORY_SCOPE_AGENT);
      __hip_atomic_store(&cs[0], tg | 0u, __ATOMIC_RELAXED, __HIP_MEMORY_SCOPE_AGENT);
    }

    for (int k = 1; k < NPOINT; ++k) {
      const int par = k & 1;

      // min-dist update + argmax. Explicit v_pk ops: dx = xs + (-px) is
      // IEEE-identical to xs - px; separate pk_mul/pk_add roundings ==
      // numpy ((dx*dx+dy*dy)+dz*dz); fminf; strict > keeps first occurrence
      // (pair order (2j, 2j+1) ascending in global index).
      float bestv = -1.0f;
      int   besti = 0;
      const f32x2 npx = {-px, -px}, npy = {-py, -py}, npz = {-pz, -pz};
#pragma unroll
      for (int j = 0; j < TPP / 2; ++j) {
        f32x2 dx, dy, dz, xx, yy, zz, s1, d;
        asm("v_pk_add_f32 %0, %1, %2" : "=v"(dx) : "v"(xs2[j]), "v"(npx));
        asm("v_pk_add_f32 %0, %1, %2" : "=v"(dy) : "v"(ys2[j]), "v"(npy));
        asm("v_pk_add_f32 %0, %1, %2" : "=v"(dz) : "v"(zs2[j]), "v"(npz));
        asm("v_pk_mul_f32 %0, %1, %1" : "=v"(xx) : "v"(dx));
        asm("v_pk_mul_f32 %0, %1, %1" : "=v"(yy) : "v"(dy));
        asm("v_pk_mul_f32 %0, %1, %1" : "=v"(zz) : "v"(dz));
        asm("v_pk_add_f32 %0, %1, %2" : "=v"(s1) : "v"(xx), "v"(yy));
        asm("v_pk_add_f32 %0, %1, %2" : "=v"(d)  : "v"(s1), "v"(zz));
        f32x2 m;
        m.x = fminf(mind2[j].x, d.x);
        m.y = fminf(mind2[j].y, d.y);
        mind2[j] = m;
        if (m.x > bestv) { bestv = m.x; besti = t + (2 * j) * THREADS; }
        if (m.y > bestv) { bestv = m.y; besti = t + (2 * j + 1) * THREADS; }
      }

      // ---- wave argmax via DPP (VALU latency): max val, then min idx
      const float    wmax = dpp_wave_max_f32(bestv);
      const unsigned cand = (bestv == wmax) ? (unsigned)besti : 0xFFFFFFFFu;
      const unsigned widx = dpp_wave_min_u32(cand);

      if (lane == 0)
        s_w[par][wid] = ((u64)__float_as_uint(wmax) << 14)
                      | (u64)((widx ^ 0x3FFFu) & 0x3FFFu);
      __syncthreads();

      // 4-level tree max over the 16 wave slots (broadcast LDS reads);
      // u64-max == (val max, idx min)
      u64 a0 = u64max(s_w[par][0],  s_w[par][1]);
      u64 a1 = u64max(s_w[par][2],  s_w[par][3]);
      u64 a2 = u64max(s_w[par][4],  s_w[par][5]);
      u64 a3 = u64max(s_w[par][6],  s_w[par][7]);
      u64 a4 = u64max(s_w[par][8],  s_w[par][9]);
      u64 a5 = u64max(s_w[par][10], s_w[par][11]);
      u64 a6 = u64max(s_w[par][12], s_w[par][13]);
      u64 a7 = u64max(s_w[par][14], s_w[par][15]);
      a0 = u64max(a0, a1); a2 = u64max(a2, a3);
      a4 = u64max(a4, a5); a6 = u64max(a6, a7);
      a0 = u64max(a0, a2); a4 = u64max(a4, a6);
      const u64 bw = u64max(a0, a4);
      const int bi = (int)((bw & 0x3FFF) ^ 0x3FFF);

      // uniform-address coord load (L2-broadcast)
      px = p[bi * 3 + 0]; py = p[bi * 3 + 1]; pz = p[bi * 3 + 2];

      if (t == 0) {
        out_inds_f[b * NPOINT + k] = (float)bi;
        const size_t o = ((size_t)b * NPOINT + k) * 3;
        out_newxyz[o + 0] = px; out_newxyz[o + 1] = py; out_newxyz[o + 2] = pz;
        const u64 tg = (u64)(CTAG | (unsigned)k) << 32;
        u64* __restrict__ ck = cs + (size_t)k * 4;
        __hip_atomic_store(&ck[1], tg | __float_as_uint(px), __ATOMIC_RELAXED, __HIP_MEMORY_SCOPE_AGENT);
        __hip_atomic_store(&ck[2], tg | __float_as_uint(py), __ATOMIC_RELAXED, __HIP_MEMORY_SCOPE_AGENT);
        __hip_atomic_store(&ck[3], tg | __float_as_uint(pz), __ATOMIC_RELAXED, __HIP_MEMORY_SCOPE_AGENT);
        __hip_atomic_store(&ck[0], tg | (unsigned)bi, __ATOMIC_RELAXED, __HIP_MEMORY_SCOPE_AGENT);
      }
      // single barrier per iter: parity double-buffer on s_w; a wave can only
      // rewrite this parity slot after passing the NEXT barrier, by which
      // time every wave has consumed this iteration's slots.
    }
    return;
  }

  // ======================= center path =======================
  const int c  = blockIdx.x - BATCH;
  const int b = c & 7, pc = c >> 3;            // pc-major: readiness ~ bid order
  const u64* __restrict__ cs = cslot + ((size_t)b * NPOINT + pc) * 4;

  // spin until this center is published (all 4 words tagged)
  if (t < 4) {
    const unsigned tg = CTAG | (unsigned)pc;
    u64 v;
    for (;;) {
      v = __hip_atomic_load(cs + t, __ATOMIC_RELAXED, __HIP_MEMORY_SCOPE_AGENT);
      if ((unsigned)(v >> 32) == tg) break;
      __builtin_amdgcn_s_sleep(8);
    }
    s_sel[t] = (unsigned)v;
  }
  __syncthreads();
  const float cx = __uint_as_float(s_sel[1]);
  const float cy = __uint_as_float(s_sel[2]);
  const float cz = __uint_as_float(s_sel[3]);
  const float* __restrict__ pb = xyz + (size_t)b * NPTS * 3;

  // ---- ball query: waves 0-3 scan disjoint quarters; exact first-64 merge.
  if (t < 256) {
    const int w = t >> 6, lane = t & 63;
    const float R2 = (float)(0.3 * 0.3);
    const int beg = w * (NPTS / 4);
    int cnt = 0, first = -1;
    for (int bs = beg; bs < beg + NPTS / 4; bs += 64) {
      const int n = bs + lane;
      const float dx = pb[n * 3 + 0] - cx;
      const float dy = pb[n * 3 + 1] - cy;
      const float dz = pb[n * 3 + 2] - cz;
      const float d = __fadd_rn(__fadd_rn(__fmul_rn(dx, dx), __fmul_rn(dy, dy)),
                                __fmul_rn(dz, dz));
      const bool in = d < R2;
      const u64 m = __ballot(in);
      if (first < 0 && m) first = bs + __ffsll(m) - 1;
      const int pos = __popcll(m & ((1ull << lane) - 1ull));
      if (in && cnt + pos < NSAMPLE) bq[w][cnt + pos] = n;
      cnt += __popcll(m);
      if (cnt >= NSAMPLE) break;
    }
    if (lane == 0) { bqcnt[w] = cnt < NSAMPLE ? cnt : NSAMPLE; bqfirst[w] = first; }
  }
  __syncthreads();
  if (t < NSAMPLE) {
    int firstAll = -1;
#pragma unroll
    for (int w = 0; w < 4; ++w)
      if (firstAll < 0 && bqfirst[w] >= 0) firstAll = bqfirst[w];
    int o = 0, val = -1;
#pragma unroll
    for (int w = 0; w < 4; ++w) {
      const int cw = bqcnt[w];
      if (val < 0 && t >= o && t < o + cw) val = bq[w][t - o];
      o += cw;
    }
    s_idx[t] = (val >= 0) ? val : firstAll;    // pad with first in-ball index
  }
  __syncthreads();

  // ---- grouping gather into LDS [ch][64] using all 16 waves
  const int sm = t & 63, cg = t >> 6;          // cg = 0..15
  const int is = s_idx[sm];
  if (cg == 0) {
    sA[0 * 64 + sm] = pb[is * 3 + 0] - cx;
    sA[1 * 64 + sm] = pb[is * 3 + 1] - cy;
    sA[2 * 64 + sm] = pb[is * 3 + 2] - cz;
  }
  const float* __restrict__ fb = feat + (size_t)b * NCH * NPTS;
  for (int ch = cg; ch < NCH; ch += 16)
    sA[(3 + ch) * 64 + sm] = fb[(size_t)ch * NPTS + is];
  __syncthreads();

  const int s0  = (t & 15) * 4;   // 4 samples
  const int oc0 = ((t >> 4) & 15) * 4;

  // ---- layer 1: CIN -> 64  (sA -> sB), waves 0-3
  if (t < 256) {
    float acc[4][4];
#pragma unroll
    for (int j = 0; j < 4; ++j) {
      const float bj = b0[oc0 + j];
#pragma unroll
      for (int i = 0; i < 4; ++i) acc[i][j] = bj;
    }
    for (int ic = 0; ic < CIN; ++ic) {
      const float4 xv = *(const float4*)&sA[ic * 64 + s0];
      const float4 wv = *(const float4*)&w0t[ic * 64 + oc0];
      const float xr[4] = {xv.x, xv.y, xv.z, xv.w};
      const float wr[4] = {wv.x, wv.y, wv.z, wv.w};
#pragma unroll
      for (int i = 0; i < 4; ++i)
#pragma unroll
        for (int j = 0; j < 4; ++j) acc[i][j] += xr[i] * wr[j];
    }
#pragma unroll
    for (int j = 0; j < 4; ++j) {
      float4 r;
      r.x = fmaxf(acc[0][j], 0.f); r.y = fmaxf(acc[1][j], 0.f);
      r.z = fmaxf(acc[2][j], 0.f); r.w = fmaxf(acc[3][j], 0.f);
      *(float4*)&sB[(oc0 + j) * 64 + s0] = r;
    }
  }
  __syncthreads();

  // ---- layer 2: 64 -> 64  (sB -> sA), waves 0-3
  if (t < 256) {
    float acc[4][4];
#pragma unroll
    for (int j = 0; j < 4; ++j) {
      const float bj = b1[oc0 + j];
#pragma unroll
      for (int i = 0; i < 4; ++i) acc[i][j] = bj;
    }
    for (int ic = 0; ic < 64; ++ic) {
      const float4 xv = *(const float4*)&sB[ic * 64 + s0];
      const float4 wv = *(const float4*)&w1t[ic * 64 + oc0];
      const float xr[4] = {xv.x, xv.y, xv.z, xv.w};
      const float wr[4] = {wv.x, wv.y, wv.z, wv.w};
#pragma unroll
      for (int i = 0; i < 4; ++i)
#pragma unroll
        for (int j = 0; j < 4; ++j) acc[i][j] += xr[i] * wr[j];
    }
#pragma unroll
    for (int j = 0; j < 4; ++j) {
      float4 r;
      r.x = fmaxf(acc[0][j], 0.f); r.y = fmaxf(acc[1][j], 0.f);
      r.z = fmaxf(acc[2][j], 0.f); r.w = fmaxf(acc[3][j], 0.f);
      *(float4*)&sA[(oc0 + j) * 64 + s0] = r;
    }
  }
  __syncthreads();

  // ---- layer 3: 64 -> 128 + max-pool over 64 samples, waves 0-3
  if (t < 256) {
    const int oc8 = ((t >> 4) & 15) * 8;
    float acc[4][8];
#pragma unroll
    for (int j = 0; j < 8; ++j) {
      const float bj = b2[oc8 + j];
#pragma unroll
      for (int i = 0; i < 4; ++i) acc[i][j] = bj;
    }
    for (int ic = 0; ic < 64; ++ic) {
      const float4 xv  = *(const float4*)&sA[ic * 64 + s0];
      const float4 wlo = *(const float4*)&w2t[ic * 128 + oc8];
      const float4 whi = *(const float4*)&w2t[ic * 128 + oc8 + 4];
      const float xr[4] = {xv.x, xv.y, xv.z, xv.w};
      const float wr[8] = {wlo.x, wlo.y, wlo.z, wlo.w, whi.x, whi.y, whi.z, whi.w};
#pragma unroll
      for (int i = 0; i < 4; ++i)
#pragma unroll
        for (int j = 0; j < 8; ++j) acc[i][j] += xr[i] * wr[j];
    }
    float m[8];
#pragma unroll
    for (int j = 0; j < 8; ++j)
      m[j] = fmaxf(fmaxf(acc[0][j], acc[1][j]), fmaxf(acc[2][j], acc[3][j]));
#pragma unroll
    for (int off = 8; off >= 1; off >>= 1) {
#pragma unroll
      for (int j = 0; j < 8; ++j)
        m[j] = fmaxf(m[j], __shfl_xor(m[j], off, 64));
    }
    if ((t & 15) == 0) {
#pragma unroll
      for (int j = 0; j < 8; ++j)
        out_feat[((size_t)b * NCH + oc8 + j) * NPOINT + pc] = fmaxf(m[j], 0.f);
    }
  }
}

// ---------------------------------------------------------------------------
extern "C" void kernel_launch(void* const* d_in, const int* in_sizes, int n_in,
                              void* d_out, int out_size, void* d_ws, size_t ws_size,
                              hipStream_t stream)
{
  const float* xyz  = (const float*)d_in[0];
  const float* feat = (const float*)d_in[1];
  const float* W0   = (const float*)d_in[2];
  const float* b0   = (const float*)d_in[3];
  const float* W1   = (const float*)d_in[4];
  const float* b1   = (const float*)d_in[5];
  const float* W2   = (const float*)d_in[6];
  const float* b2   = (const float*)d_in[7];

  float* out_newxyz = (float*)d_out;                               // 8*1024*3
  float* out_feat   = out_newxyz + (size_t)BATCH * NPOINT * 3;     // 8*128*1024
  float* out_inds_f = out_feat + (size_t)BATCH * NCH * NPOINT;     // 8*1024

  char* ws = (char*)d_ws;
  u64* cslot = (u64*)ws;                                // 8192*4 u64 = 256 KB
  float* w0t = (float*)(ws + 262144);
  float* w1t = w0t + 64 * CIN;
  float* w2t = w1t + 64 * 64;

  hipMemsetAsync(cslot, 0, 262144, stream);             // clear center tags
  wtrans_kernel<<<dim3((64 * CIN + 255) / 256), dim3(256), 0, stream>>>(
      W0, W1, W2, w0t, w1t, w2t);
  mega_kernel<<<dim3(BATCH + BATCH * NPOINT), dim3(THREADS), 0, stream>>>(
      xyz, feat, w0t, b0, w1t, b1, w2t, b2,
      out_newxyz, out_feat, out_inds_f, cslot);
}

// Round 17
// 1836.531 us; speedup vs baseline: 1.1683x; 1.1683x over previous
//
#include <hip/hip_runtime.h>

#define BATCH   8
#define NPTS    16384
#define NCH     128
#define NPOINT  1024
#define NSAMPLE 64
#define CIN     131   // 3 + NCH

#define THREADS  1024
#define TPP      (NPTS / THREADS)   // 16 points per thread (8 float2 pairs)
#define CTAG     0x7C000000u

typedef unsigned long long u64;
typedef float f32x2 __attribute__((ext_vector_type(2)));

__device__ __forceinline__ u64 u64max(u64 a, u64 b) { return a > b ? a : b; }

// 64-lane f32 max via DPP (VALU latency). xor1,xor2 (quad_perm), row_half_
// mirror, row_mirror, row_bcast15, row_bcast31; result uniform via readlane 63.
__device__ __forceinline__ float dpp_wave_max_f32(float v) {
  float o;
  o = __int_as_float(__builtin_amdgcn_update_dpp(
        __float_as_int(v), __float_as_int(v), 0xB1, 0xF, 0xF, false));
  v = fmaxf(v, o);
  o = __int_as_float(__builtin_amdgcn_update_dpp(
        __float_as_int(v), __float_as_int(v), 0x4E, 0xF, 0xF, false));
  v = fmaxf(v, o);
  o = __int_as_float(__builtin_amdgcn_update_dpp(
        __float_as_int(v), __float_as_int(v), 0x141, 0xF, 0xF, false));
  v = fmaxf(v, o);
  o = __int_as_float(__builtin_amdgcn_update_dpp(
        __float_as_int(v), __float_as_int(v), 0x140, 0xF, 0xF, false));
  v = fmaxf(v, o);
  o = __int_as_float(__builtin_amdgcn_update_dpp(
        __float_as_int(v), __float_as_int(v), 0x142, 0xF, 0xF, false));
  v = fmaxf(v, o);
  o = __int_as_float(__builtin_amdgcn_update_dpp(
        __float_as_int(v), __float_as_int(v), 0x143, 0xF, 0xF, false));
  v = fmaxf(v, o);
  return __int_as_float(__builtin_amdgcn_readlane(__float_as_int(v), 63));
}

__device__ __forceinline__ unsigned dpp_wave_min_u32(unsigned v) {
  unsigned o;
  o = (unsigned)__builtin_amdgcn_update_dpp((int)v, (int)v, 0xB1, 0xF, 0xF, false);
  v = min(v, o);
  o = (unsigned)__builtin_amdgcn_update_dpp((int)v, (int)v, 0x4E, 0xF, 0xF, false);
  v = min(v, o);
  o = (unsigned)__builtin_amdgcn_update_dpp((int)v, (int)v, 0x141, 0xF, 0xF, false);
  v = min(v, o);
  o = (unsigned)__builtin_amdgcn_update_dpp((int)v, (int)v, 0x140, 0xF, 0xF, false);
  v = min(v, o);
  o = (unsigned)__builtin_amdgcn_update_dpp((int)v, (int)v, 0x142, 0xF, 0xF, false);
  v = min(v, o);
  o = (unsigned)__builtin_amdgcn_update_dpp((int)v, (int)v, 0x143, 0xF, 0xF, false);
  v = min(v, o);
  return (unsigned)__builtin_amdgcn_readlane((int)v, 63);
}

// ---------------------------------------------------------------------------
// Transpose weights into [ic][oc] layout (float4 loads in the MLP).
// ---------------------------------------------------------------------------
__global__ void wtrans_kernel(const float* __restrict__ W0,
                              const float* __restrict__ W1,
                              const float* __restrict__ W2,
                              float* __restrict__ w0t,
                              float* __restrict__ w1t,
                              float* __restrict__ w2t)
{
  const int t = blockIdx.x * blockDim.x + threadIdx.x;
  if (t < 64 * CIN) { const int oc = t / CIN, ic = t % CIN; w0t[ic * 64  + oc] = W0[t]; }
  if (t < 64 * 64)  { const int oc = t >> 6,  ic = t & 63;  w1t[ic * 64  + oc] = W1[t]; }
  if (t < 128 * 64) { const int oc = t / 64,  ic = t % 64;  w2t[ic * 128 + oc] = W2[t]; }
}

// ---------------------------------------------------------------------------
// Mega kernel (R15 inner loop). DVFS experiment: consumer blocks BUSY-wait
// (all 1024 threads run dummy FMA between tag polls, block consensus via
// __syncthreads_and) so the chip looks active and SCLK boosts — the FPS
// critical path is hypothesized clock-starved (models consistently ~2x fast
// at 2.4 GHz). LDS is padded to ~82 KB so exactly ONE block/CU: busy
// consumers can never co-reside with (and steal issue from) FPS blocks.
// bids 0..7: FPS, one block per batch; ONE barrier/iter (parity LDS);
// DPP wave argmax; uniform coord load. bids 8..8199: one block per center
// (pc-major): busy-spin on tagged slot -> ballquery -> gather -> MLP.
// ---------------------------------------------------------------------------
__global__ __launch_bounds__(THREADS) void mega_kernel(
    const float* __restrict__ xyz, const float* __restrict__ feat,
    const float* __restrict__ w0t, const float* __restrict__ b0,
    const float* __restrict__ w1t, const float* __restrict__ b1,
    const float* __restrict__ w2t, const float* __restrict__ b2,
    float* __restrict__ out_newxyz, float* __restrict__ out_feat,
    float* __restrict__ out_inds_f, u64* __restrict__ cslot)
{
  __shared__ float sA[CIN * 64];     // grouped x (131x64); reused as h2
  __shared__ float sB[64 * 64];      // h1
  __shared__ int   s_idx[NSAMPLE];
  __shared__ int   bq[4][NSAMPLE];
  __shared__ int   bqcnt[4], bqfirst[4];
  __shared__ u64   s_w[2][16];
  __shared__ unsigned s_sel[4];
  __shared__ u64   lds_pad[3800];    // occupancy limiter: ~82 KB -> 1 blk/CU

  const int t = threadIdx.x;
  { volatile u64* vp = lds_pad; vp[t] = (u64)t; }   // keep pad alive

  if (blockIdx.x < BATCH) {
    // ======================= FPS path (exclusive CU) =======================
    const int b = blockIdx.x;
    const int lane = t & 63, wid = t >> 6;
    const float* __restrict__ p = xyz + (size_t)b * NPTS * 3;

    f32x2 xs2[TPP / 2], ys2[TPP / 2], zs2[TPP / 2], mind2[TPP / 2];
#pragma unroll
    for (int j = 0; j < TPP / 2; ++j) {
      const int n0 = t + (2 * j) * THREADS;      // coalesced per wave
      const int n1 = t + (2 * j + 1) * THREADS;
      xs2[j] = (f32x2){p[n0 * 3 + 0], p[n1 * 3 + 0]};
      ys2[j] = (f32x2){p[n0 * 3 + 1], p[n1 * 3 + 1]};
      zs2[j] = (f32x2){p[n0 * 3 + 2], p[n1 * 3 + 2]};
      mind2[j] = (f32x2){1e10f, 1e10f};
    }

    u64* __restrict__ cs = cslot + (size_t)b * NPOINT * 4;

    float px = p[0], py = p[1], pz = p[2];
    if (t == 0) {
      out_inds_f[b * NPOINT] = 0.0f;
      const size_t o = (size_t)b * NPOINT * 3;
      out_newxyz[o + 0] = px; out_newxyz[o + 1] = py; out_newxyz[o + 2] = pz;
      const u64 tg = (u64)CTAG << 32;
      __hip_atomic_store(&cs[1], tg | __float_as_uint(px), __ATOMIC_RELAXED, __HIP_MEMORY_SCOPE_AGENT);
      __hip_atomic_store(&cs[2], tg | __float_as_uint(py), __ATOMIC_RELAXED, __HIP_MEMORY_SCOPE_AGENT);
      __hip_atomic_store(&cs[3], tg | __float_as_uint(pz), __ATOMIC_RELAXED, __HIP_MEMORY_SCOPE_AGENT);
      __hip_atomic_store(&cs[0], tg | 0u, __ATOMIC_RELAXED, __HIP_MEMORY_SCOPE_AGENT);
    }

    for (int k = 1; k < NPOINT; ++k) {
      const int par = k & 1;

      // min-dist update + argmax. float2 pairs; contract(off) keeps separate
      // IEEE mul/add per component == numpy ((dx*dx+dy*dy)+dz*dz), no fma.
      // Pair order (2j, 2j+1) ascending => strict > keeps first occurrence.
      float bestv = -1.0f;
      int   besti = 0;
      const f32x2 px2 = {px, px}, py2 = {py, py}, pz2 = {pz, pz};
#pragma unroll
      for (int j = 0; j < TPP / 2; ++j) {
#pragma clang fp contract(off)
        const f32x2 dx = xs2[j] - px2;
        const f32x2 dy = ys2[j] - py2;
        const f32x2 dz = zs2[j] - pz2;
        const f32x2 d  = dx * dx + dy * dy + dz * dz;
        f32x2 m;
        m.x = fminf(mind2[j].x, d.x);
        m.y = fminf(mind2[j].y, d.y);
        mind2[j] = m;
        if (m.x > bestv) { bestv = m.x; besti = t + (2 * j) * THREADS; }
        if (m.y > bestv) { bestv = m.y; besti = t + (2 * j + 1) * THREADS; }
      }

      // ---- wave argmax via DPP (VALU latency): max val, then min idx
      const float    wmax = dpp_wave_max_f32(bestv);
      const unsigned cand = (bestv == wmax) ? (unsigned)besti : 0xFFFFFFFFu;
      const unsigned widx = dpp_wave_min_u32(cand);

      if (lane == 0)
        s_w[par][wid] = ((u64)__float_as_uint(wmax) << 14)
                      | (u64)((widx ^ 0x3FFFu) & 0x3FFFu);
      __syncthreads();

      // 4-level tree max over the 16 wave slots (broadcast LDS reads);
      // u64-max == (val max, idx min)
      u64 a0 = u64max(s_w[par][0],  s_w[par][1]);
      u64 a1 = u64max(s_w[par][2],  s_w[par][3]);
      u64 a2 = u64max(s_w[par][4],  s_w[par][5]);
      u64 a3 = u64max(s_w[par][6],  s_w[par][7]);
      u64 a4 = u64max(s_w[par][8],  s_w[par][9]);
      u64 a5 = u64max(s_w[par][10], s_w[par][11]);
      u64 a6 = u64max(s_w[par][12], s_w[par][13]);
      u64 a7 = u64max(s_w[par][14], s_w[par][15]);
      a0 = u64max(a0, a1); a2 = u64max(a2, a3);
      a4 = u64max(a4, a5); a6 = u64max(a6, a7);
      a0 = u64max(a0, a2); a4 = u64max(a4, a6);
      const u64 bw = u64max(a0, a4);
      const int bi = (int)((bw & 0x3FFF) ^ 0x3FFF);

      // uniform-address coord load (L2-broadcast)
      px = p[bi * 3 + 0]; py = p[bi * 3 + 1]; pz = p[bi * 3 + 2];

      if (t == 0) {
        out_inds_f[b * NPOINT + k] = (float)bi;
        const size_t o = ((size_t)b * NPOINT + k) * 3;
        out_newxyz[o + 0] = px; out_newxyz[o + 1] = py; out_newxyz[o + 2] = pz;
        const u64 tg = (u64)(CTAG | (unsigned)k) << 32;
        u64* __restrict__ ck = cs + (size_t)k * 4;
        __hip_atomic_store(&ck[1], tg | __float_as_uint(px), __ATOMIC_RELAXED, __HIP_MEMORY_SCOPE_AGENT);
        __hip_atomic_store(&ck[2], tg | __float_as_uint(py), __ATOMIC_RELAXED, __HIP_MEMORY_SCOPE_AGENT);
        __hip_atomic_store(&ck[3], tg | __float_as_uint(pz), __ATOMIC_RELAXED, __HIP_MEMORY_SCOPE_AGENT);
        __hip_atomic_store(&ck[0], tg | (unsigned)bi, __ATOMIC_RELAXED, __HIP_MEMORY_SCOPE_AGENT);
      }
      // single barrier per iter: parity double-buffer on s_w; a wave can only
      // rewrite this parity slot after passing the NEXT barrier, by which
      // time every wave has consumed this iteration's slots.
    }
    return;
  }

  // ======================= center path =======================
  const int c  = blockIdx.x - BATCH;
  const int b = c & 7, pc = c >> 3;            // pc-major: readiness ~ bid order
  const u64* __restrict__ cs = cslot + ((size_t)b * NPOINT + pc) * 4;

  // BUSY spin until this center is published: lanes 0-3 poll the 4 tagged
  // words; all other threads run dummy FMA so the CU reports high activity
  // (DVFS boost); block-wide consensus via __syncthreads_and each round.
  {
    const unsigned tg = CTAG | (unsigned)pc;
    float dummy = (float)t;
    for (;;) {
      int ok = 1;
      if (t < 4) {
        const u64 v = __hip_atomic_load(cs + t, __ATOMIC_RELAXED,
                                        __HIP_MEMORY_SCOPE_AGENT);
        ok = ((unsigned)(v >> 32) == tg) ? 1 : 0;
        if (ok) s_sel[t] = (unsigned)v;
      }
      if (__syncthreads_and(ok)) break;
#pragma unroll
      for (int i = 0; i < 64; ++i)
        dummy = __builtin_fmaf(dummy, 1.0000001f, 0.0000001f);
    }
    asm volatile("" :: "v"(dummy));   // keep the busy work alive
  }
  __syncthreads();
  const float cx = __uint_as_float(s_sel[1]);
  const float cy = __uint_as_float(s_sel[2]);
  const float cz = __uint_as_float(s_sel[3]);
  const float* __restrict__ pb = xyz + (size_t)b * NPTS * 3;

  // ---- ball query: waves 0-3 scan disjoint quarters; exact first-64 merge.
  if (t < 256) {
    const int w = t >> 6, lane = t & 63;
    const float R2 = (float)(0.3 * 0.3);
    const int beg = w * (NPTS / 4);
    int cnt = 0, first = -1;
    for (int bs = beg; bs < beg + NPTS / 4; bs += 64) {
      const int n = bs + lane;
      const float dx = pb[n * 3 + 0] - cx;
      const float dy = pb[n * 3 + 1] - cy;
      const float dz = pb[n * 3 + 2] - cz;
      const float d = __fadd_rn(__fadd_rn(__fmul_rn(dx, dx), __fmul_rn(dy, dy)),
                                __fmul_rn(dz, dz));
      const bool in = d < R2;
      const u64 m = __ballot(in);
      if (first < 0 && m) first = bs + __ffsll(m) - 1;
      const int pos = __popcll(m & ((1ull << lane) - 1ull));
      if (in && cnt + pos < NSAMPLE) bq[w][cnt + pos] = n;
      cnt += __popcll(m);
      if (cnt >= NSAMPLE) break;
    }
    if (lane == 0) { bqcnt[w] = cnt < NSAMPLE ? cnt : NSAMPLE; bqfirst[w] = first; }
  }
  __syncthreads();
  if (t < NSAMPLE) {
    int firstAll = -1;
#pragma unroll
    for (int w = 0; w < 4; ++w)
      if (firstAll < 0 && bqfirst[w] >= 0) firstAll = bqfirst[w];
    int o = 0, val = -1;
#pragma unroll
    for (int w = 0; w < 4; ++w) {
      const int cw = bqcnt[w];
      if (val < 0 && t >= o && t < o + cw) val = bq[w][t - o];
      o += cw;
    }
    s_idx[t] = (val >= 0) ? val : firstAll;    // pad with first in-ball index
  }
  __syncthreads();

  // ---- grouping gather into LDS [ch][64] using all 16 waves
  const int sm = t & 63, cg = t >> 6;          // cg = 0..15
  const int is = s_idx[sm];
  if (cg == 0) {
    sA[0 * 64 + sm] = pb[is * 3 + 0] - cx;
    sA[1 * 64 + sm] = pb[is * 3 + 1] - cy;
    sA[2 * 64 + sm] = pb[is * 3 + 2] - cz;
  }
  const float* __restrict__ fb = feat + (size_t)b * NCH * NPTS;
  for (int ch = cg; ch < NCH; ch += 16)
    sA[(3 + ch) * 64 + sm] = fb[(size_t)ch * NPTS + is];
  __syncthreads();

  const int s0  = (t & 15) * 4;   // 4 samples
  const int oc0 = ((t >> 4) & 15) * 4;

  // ---- layer 1: CIN -> 64  (sA -> sB), waves 0-3
  if (t < 256) {
    float acc[4][4];
#pragma unroll
    for (int j = 0; j < 4; ++j) {
      const float bj = b0[oc0 + j];
#pragma unroll
      for (int i = 0; i < 4; ++i) acc[i][j] = bj;
    }
    for (int ic = 0; ic < CIN; ++ic) {
      const float4 xv = *(const float4*)&sA[ic * 64 + s0];
      const float4 wv = *(const float4*)&w0t[ic * 64 + oc0];
      const float xr[4] = {xv.x, xv.y, xv.z, xv.w};
      const float wr[4] = {wv.x, wv.y, wv.z, wv.w};
#pragma unroll
      for (int i = 0; i < 4; ++i)
#pragma unroll
        for (int j = 0; j < 4; ++j) acc[i][j] += xr[i] * wr[j];
    }
#pragma unroll
    for (int j = 0; j < 4; ++j) {
      float4 r;
      r.x = fmaxf(acc[0][j], 0.f); r.y = fmaxf(acc[1][j], 0.f);
      r.z = fmaxf(acc[2][j], 0.f); r.w = fmaxf(acc[3][j], 0.f);
      *(float4*)&sB[(oc0 + j) * 64 + s0] = r;
    }
  }
  __syncthreads();

  // ---- layer 2: 64 -> 64  (sB -> sA), waves 0-3
  if (t < 256) {
    float acc[4][4];
#pragma unroll
    for (int j = 0; j < 4; ++j) {
      const float bj = b1[oc0 + j];
#pragma unroll
      for (int i = 0; i < 4; ++i) acc[i][j] = bj;
    }
    for (int ic = 0; ic < 64; ++ic) {
      const float4 xv = *(const float4*)&sB[ic * 64 + s0];
      const float4 wv = *(const float4*)&w1t[ic * 64 + oc0];
      const float xr[4] = {xv.x, xv.y, xv.z, xv.w};
      const float wr[4] = {wv.x, wv.y, wv.z, wv.w};
#pragma unroll
      for (int i = 0; i < 4; ++i)
#pragma unroll
        for (int j = 0; j < 4; ++j) acc[i][j] += xr[i] * wr[j];
    }
#pragma unroll
    for (int j = 0; j < 4; ++j) {
      float4 r;
      r.x = fmaxf(acc[0][j], 0.f); r.y = fmaxf(acc[1][j], 0.f);
      r.z = fmaxf(acc[2][j], 0.f); r.w = fmaxf(acc[3][j], 0.f);
      *(float4*)&sA[(oc0 + j) * 64 + s0] = r;
    }
  }
  __syncthreads();

  // ---- layer 3: 64 -> 128 + max-pool over 64 samples, waves 0-3
  if (t < 256) {
    const int oc8 = ((t >> 4) & 15) * 8;
    float acc[4][8];
#pragma unroll
    for (int j = 0; j < 8; ++j) {
      const float bj = b2[oc8 + j];
#pragma unroll
      for (int i = 0; i < 4; ++i) acc[i][j] = bj;
    }
    for (int ic = 0; ic < 64; ++ic) {
      const float4 xv  = *(const float4*)&sA[ic * 64 + s0];
      const float4 wlo = *(const float4*)&w2t[ic * 128 + oc8];
      const float4 whi = *(const float4*)&w2t[ic * 128 + oc8 + 4];
      const float xr[4] = {xv.x, xv.y, xv.z, xv.w};
      const float wr[8] = {wlo.x, wlo.y, wlo.z, wlo.w, whi.x, whi.y, whi.z, whi.w};
#pragma unroll
      for (int i = 0; i < 4; ++i)
#pragma unroll
        for (int j = 0; j < 8; ++j) acc[i][j] += xr[i] * wr[j];
    }
    float m[8];
#pragma unroll
    for (int j = 0; j < 8; ++j)
      m[j] = fmaxf(fmaxf(acc[0][j], acc[1][j]), fmaxf(acc[2][j], acc[3][j]));
#pragma unroll
    for (int off = 8; off >= 1; off >>= 1) {
#pragma unroll
      for (int j = 0; j < 8; ++j)
        m[j] = fmaxf(m[j], __shfl_xor(m[j], off, 64));
    }
    if ((t & 15) == 0) {
#pragma unroll
      for (int j = 0; j < 8; ++j)
        out_feat[((size_t)b * NCH + oc8 + j) * NPOINT + pc] = fmaxf(m[j], 0.f);
    }
  }
}

// ---------------------------------------------------------------------------
extern "C" void kernel_launch(void* const* d_in, const int* in_sizes, int n_in,
                              void* d_out, int out_size, void* d_ws, size_t ws_size,
                              hipStream_t stream)
{
  const float* xyz  = (const float*)d_in[0];
  const float* feat = (const float*)d_in[1];
  const float* W0   = (const float*)d_in[2];
  const float* b0   = (const float*)d_in[3];
  const float* W1   = (const float*)d_in[4];
  const float* b1   = (const float*)d_in[5];
  const float* W2   = (const float*)d_in[6];
  const float* b2   = (const float*)d_in[7];

  float* out_newxyz = (float*)d_out;                               // 8*1024*3
  float* out_feat   = out_newxyz + (size_t)BATCH * NPOINT * 3;     // 8*128*1024
  float* out_inds_f = out_feat + (size_t)BATCH * NCH * NPOINT;     // 8*1024

  char* ws = (char*)d_ws;
  u64* cslot = (u64*)ws;                                // 8192*4 u64 = 256 KB
  float* w0t = (float*)(ws + 262144);
  float* w1t = w0t + 64 * CIN;
  float* w2t = w1t + 64 * 64;

  hipMemsetAsync(cslot, 0, 262144, stream);             // clear center tags
  wtrans_kernel<<<dim3((64 * CIN + 255) / 256), dim3(256), 0, stream>>>(
      W0, W1, W2, w0t, w1t, w2t);
  mega_kernel<<<dim3(BATCH + BATCH * NPOINT), dim3(THREADS), 0, stream>>>(
      xyz, feat, w0t, b0, w1t, b1, w2t, b2,
      out_newxyz, out_feat, out_inds_f, cslot);
}